// Round 2
// baseline (76.856 us; speedup 1.0000x reference)
//
#include <hip/hip_runtime.h>

// DifferentiableHistogram: x (4,3,256,256) fp32, bin_centers (512,3) fp32
// (separable 8x8x8 grid), out (4,512) fp32.
//
// exp(-||p-c_ijk||^2 * 1250) = ex_i*ey_j*ez_k; per-pixel denom = sx*sy*sz.
// Kernel 1: per-block (256 pixels) partial histograms -> d_ws (no atomics,
//           no d_out zeroing needed).
// Kernel 2: reduce 256 partials/batch + L1-normalize -> d_out.
//
// NOTE (round 1 post-mortem): harness poisons d_ws (256 MB) inside the timed
// window -> ~40.7 us fillBuffer floor we cannot remove. Optimize accum only.

#define NPIX  65536        // 256*256
#define NB    4
#define BPB   256          // blocks per batch; 256 pixels per block (one tile)
#define STR   8            // LDS row stride in floats (32 B, b128-aligned)

__global__ __launch_bounds__(256) void hist_accum(
    const float* __restrict__ x, const float* __restrict__ bc,
    float* __restrict__ ws)
{
    __shared__ float s_ex[256][STR];   // ex[i] * invS
    __shared__ float s_ey[256][STR];
    __shared__ float s_ez[256][STR];
    __shared__ float s_red[4][512];    // team partials, packed q=(j*8+k)*8+i

    const int tid   = threadIdx.x;
    const int b     = blockIdx.x >> 8;           // BPB == 256
    const int chunk = blockIdx.x & (BPB - 1);
    const int p     = chunk * 256 + tid;

    // bin center coords per dim: bin (i,j,k) -> row i*64+j*8+k = (c_i,c_j,c_k)
    float cx[8], cy[8], cz[8];
#pragma unroll
    for (int i = 0; i < 8; ++i) {
        cx[i] = bc[i * 192 + 0];
        cy[i] = bc[i * 24 + 1];
        cz[i] = bc[i * 3 + 2];
    }

    // ---- stage: one pixel per thread ----
    const float* xb = x + (size_t)b * 3 * NPIX;
    const float r  = xb[p];
    const float g  = xb[NPIX + p];
    const float bl = xb[2 * NPIX + p];
    float ex[8], ey[8], ez[8];
    float sx = 0.f, sy = 0.f, sz = 0.f;
#pragma unroll
    for (int i = 0; i < 8; ++i) {
        float dx = r  - cx[i]; ex[i] = __expf(dx * dx * -1250.0f); sx += ex[i];
        float dy = g  - cy[i]; ey[i] = __expf(dy * dy * -1250.0f); sy += ey[i];
        float dz = bl - cz[i]; ez[i] = __expf(dz * dz * -1250.0f); sz += ez[i];
    }
    const float invS = 1.0f / (sx * sy * sz + 1e-8f);
    // float4 stores: 16 lanes cover 64 consecutive words -> 2-way (free)
    ((float4*)s_ex[tid])[0] = make_float4(ex[0]*invS, ex[1]*invS, ex[2]*invS, ex[3]*invS);
    ((float4*)s_ex[tid])[1] = make_float4(ex[4]*invS, ex[5]*invS, ex[6]*invS, ex[7]*invS);
    ((float4*)s_ey[tid])[0] = make_float4(ey[0], ey[1], ey[2], ey[3]);
    ((float4*)s_ey[tid])[1] = make_float4(ey[4], ey[5], ey[6], ey[7]);
    ((float4*)s_ez[tid])[0] = make_float4(ez[0], ez[1], ez[2], ez[3]);
    ((float4*)s_ez[tid])[1] = make_float4(ez[4], ez[5], ez[6], ez[7]);
    __syncthreads();

    // ---- accumulate: each team (wave) sweeps 64 pixels; lane owns (jj,kk,i=0..7)
    const int team = tid >> 6;
    const int lane = tid & 63;
    const int jj   = lane >> 3;
    const int kk   = lane & 7;
    const int pbase = team * 64;

    float acc[8];
#pragma unroll
    for (int i = 0; i < 8; ++i) acc[i] = 0.f;

#pragma unroll 8
    for (int q = 0; q < 64; ++q) {
        const int pp = pbase + q;
        const float eyz = s_ey[pp][jj] * s_ez[pp][kk];     // 8-bank broadcast
        const float4 a0 = *(const float4*)&s_ex[pp][0];    // uniform b128 bcast
        const float4 a1 = *(const float4*)&s_ex[pp][4];
        acc[0] += a0.x * eyz; acc[1] += a0.y * eyz;
        acc[2] += a0.z * eyz; acc[3] += a0.w * eyz;
        acc[4] += a1.x * eyz; acc[5] += a1.y * eyz;
        acc[6] += a1.z * eyz; acc[7] += a1.w * eyz;
    }

    // ---- reduce 4 teams -> block partial -> d_ws (packed-q order) ----
#pragma unroll
    for (int i = 0; i < 8; ++i) s_red[team][lane * 8 + i] = acc[i];
    __syncthreads();

    for (int q = tid; q < 512; q += 256) {
        const float v = s_red[0][q] + s_red[1][q] + s_red[2][q] + s_red[3][q];
        ws[(size_t)blockIdx.x * 512 + q] = v;
    }
}

// Reduce 256 partials per batch + L1-normalize. 4 blocks x 512 threads.
__global__ __launch_bounds__(512) void hist_reduce(
    const float* __restrict__ ws, float* __restrict__ out)
{
    const int b = blockIdx.x;
    const int q = threadIdx.x;                 // packed index (j*8+k)*8+i
    const float* wb = ws + (size_t)b * BPB * 512;

    float v = 0.f;
#pragma unroll 8
    for (int c = 0; c < BPB; ++c) v += wb[c * 512 + q];

    // block sum of v over 512 threads
    float s = v;
#pragma unroll
    for (int off = 32; off > 0; off >>= 1) s += __shfl_down(s, off, 64);
    __shared__ float red[8];
    if ((q & 63) == 0) red[q >> 6] = s;
    __syncthreads();
    float S = 0.f;
#pragma unroll
    for (int i = 0; i < 8; ++i) S += red[i];

    const int bin = ((q & 7) << 6) | (q >> 3);   // i*64 + j*8 + k
    out[b * 512 + bin] = v / (S + 1e-8f);
}

extern "C" void kernel_launch(void* const* d_in, const int* in_sizes, int n_in,
                              void* d_out, int out_size, void* d_ws, size_t ws_size,
                              hipStream_t stream) {
    const float* x  = (const float*)d_in[0];
    const float* bc = (const float*)d_in[1];
    float* ws  = (float*)d_ws;    // 4*256*512*4 B = 2 MB partials (fully written)
    float* out = (float*)d_out;

    hist_accum<<<dim3(NB * BPB), dim3(256), 0, stream>>>(x, bc, ws);
    hist_reduce<<<dim3(NB), dim3(512), 0, stream>>>(ws, out);
}

// Round 3
// 66.980 us; speedup vs baseline: 1.1474x; 1.1474x over previous
//
#include <hip/hip_runtime.h>

// DifferentiableHistogram: x (4,3,256,256) fp32, bin_centers (512,3) fp32
// (separable 8x8x8 grid), out (4,512) fp32.
//
// exp(-||p-c_ijk||^2 * 1250) = ex_i*ey_j*ez_k; per-pixel denom = sx*sy*sz.
//
// R2 post-mortem: ~40.5 us of dur is the harness poisoning 256 MB d_ws
// (fillBufferAligned) inside the timed window -- unavoidable floor.
// Accum was LDS-pipe bound (36 cyc/pixel of broadcast reads). This round:
//  - ex'[] broadcast via v_readlane (VALU pipe, wave sweeps its OWN pixels)
//  - ey/ez staged TRANSPOSED -> one ds_read_b128 covers 4 pixels
//    (row stride 260 words: jj*260 % 32 = jj*4 -> 8 rows hit disjoint banks)
//  - two-level reduce (64 blocks then 4) instead of one 4-block kernel.

#define NPIX  65536
#define NB    4
#define BPB   256          // blocks per batch; 256 pixels per block
#define RSTR  260          // transposed LDS row stride (words); 1040 B, 16B-aligned

__device__ __forceinline__ float readlane_f(float v, int l) {
    return __int_as_float(__builtin_amdgcn_readlane(__float_as_int(v), l));
}

__global__ __launch_bounds__(256) void hist_accum(
    const float* __restrict__ x, const float* __restrict__ bc,
    float* __restrict__ ws)
{
    __shared__ __align__(16) float s_ey[8][RSTR];
    __shared__ __align__(16) float s_ez[8][RSTR];
    __shared__ float s_red[4][512];

    const int tid   = threadIdx.x;
    const int b     = blockIdx.x >> 8;
    const int chunk = blockIdx.x & (BPB - 1);
    const int p     = chunk * 256 + tid;

    float cx[8], cy[8], cz[8];
#pragma unroll
    for (int i = 0; i < 8; ++i) {
        cx[i] = bc[i * 192 + 0];   // bin (i,j,k) at row i*64+j*8+k
        cy[i] = bc[i * 24 + 1];
        cz[i] = bc[i * 3 + 2];
    }

    // ---- stage: one pixel per thread ----
    const float* xb = x + (size_t)b * 3 * NPIX;
    const float r  = xb[p];
    const float g  = xb[NPIX + p];
    const float bl = xb[2 * NPIX + p];
    float exn[8], ey[8], ez[8];
    float sx = 0.f, sy = 0.f, sz = 0.f;
#pragma unroll
    for (int i = 0; i < 8; ++i) {
        float dx = r  - cx[i]; exn[i] = __expf(dx * dx * -1250.0f); sx += exn[i];
        float dy = g  - cy[i]; ey[i]  = __expf(dy * dy * -1250.0f); sy += ey[i];
        float dz = bl - cz[i]; ez[i]  = __expf(dz * dz * -1250.0f); sz += ez[i];
    }
    const float invS = 1.0f / (sx * sy * sz + 1e-8f);
#pragma unroll
    for (int i = 0; i < 8; ++i) {
        exn[i] *= invS;            // stays in this lane's VGPRs (readlane source)
        s_ey[i][tid] = ey[i];      // transposed; coalesced b32 writes
        s_ez[i][tid] = ez[i];
    }
    __syncthreads();

    // ---- sweep: wave handles its OWN 64 staged pixels; lane owns (jj,kk,i=0..7)
    const int team = tid >> 6;
    const int lane = tid & 63;
    const int jj   = lane >> 3;
    const int kk   = lane & 7;
    const int q0   = team * 64;

    float acc[8];
#pragma unroll
    for (int i = 0; i < 8; ++i) acc[i] = 0.f;

#pragma unroll
    for (int q4 = 0; q4 < 64; q4 += 4) {
        const float4 eyv = *(const float4*)&s_ey[jj][q0 + q4];  // 4 pixels/read
        const float4 ezv = *(const float4*)&s_ez[kk][q0 + q4];
        const float eyz0 = eyv.x * ezv.x;
        const float eyz1 = eyv.y * ezv.y;
        const float eyz2 = eyv.z * ezv.z;
        const float eyz3 = eyv.w * ezv.w;
#pragma unroll
        for (int i = 0; i < 8; ++i) {
            acc[i] += eyz0 * readlane_f(exn[i], q4 + 0);
            acc[i] += eyz1 * readlane_f(exn[i], q4 + 1);
            acc[i] += eyz2 * readlane_f(exn[i], q4 + 2);
            acc[i] += eyz3 * readlane_f(exn[i], q4 + 3);
        }
    }

    // ---- reduce 4 teams -> block partial -> ws (packed q=(j*8+k)*8+i) ----
#pragma unroll
    for (int i = 0; i < 8; ++i) s_red[team][lane * 8 + i] = acc[i];
    __syncthreads();

    for (int q = tid; q < 512; q += 256) {
        const float v = s_red[0][q] + s_red[1][q] + s_red[2][q] + s_red[3][q];
        ws[(size_t)blockIdx.x * 512 + q] = v;
    }
}

// Level-1 reduce: 64 blocks; block (b,s) sums 16 of the 256 chunks of batch b.
__global__ __launch_bounds__(256) void hist_reduce1(
    const float* __restrict__ ws, float* __restrict__ ws2)
{
    const int b = blockIdx.x >> 4;
    const int s = blockIdx.x & 15;
    const float* wb = ws + ((size_t)b * BPB + s * 16) * 512;

#pragma unroll
    for (int h = 0; h < 2; ++h) {
        const int q = h * 256 + threadIdx.x;
        float v = 0.f;
#pragma unroll
        for (int c = 0; c < 16; ++c) v += wb[c * 512 + q];
        ws2[(size_t)blockIdx.x * 512 + q] = v;
    }
}

// Level-2 reduce + L1 normalize: 4 blocks x 512 threads.
__global__ __launch_bounds__(512) void hist_reduce2(
    const float* __restrict__ ws2, float* __restrict__ out)
{
    const int b = blockIdx.x;
    const int q = threadIdx.x;               // packed (j*8+k)*8+i
    const float* wb = ws2 + (size_t)b * 16 * 512;

    float v = 0.f;
#pragma unroll
    for (int s = 0; s < 16; ++s) v += wb[s * 512 + q];

    float s = v;
#pragma unroll
    for (int off = 32; off > 0; off >>= 1) s += __shfl_down(s, off, 64);
    __shared__ float red[8];
    if ((q & 63) == 0) red[q >> 6] = s;
    __syncthreads();
    float S = 0.f;
#pragma unroll
    for (int i = 0; i < 8; ++i) S += red[i];

    const int bin = ((q & 7) << 6) | (q >> 3);   // i*64 + j*8 + k
    out[b * 512 + bin] = v / (S + 1e-8f);
}

extern "C" void kernel_launch(void* const* d_in, const int* in_sizes, int n_in,
                              void* d_out, int out_size, void* d_ws, size_t ws_size,
                              hipStream_t stream) {
    const float* x  = (const float*)d_in[0];
    const float* bc = (const float*)d_in[1];
    float* ws  = (float*)d_ws;                    // 1024*512 floats = 2 MB
    float* ws2 = (float*)d_ws + 1024 * 512;       // 64*512 floats = 128 KB
    float* out = (float*)d_out;

    hist_accum<<<dim3(NB * BPB), dim3(256), 0, stream>>>(x, bc, ws);
    hist_reduce1<<<dim3(64), dim3(256), 0, stream>>>(ws, ws2);
    hist_reduce2<<<dim3(NB), dim3(512), 0, stream>>>(ws2, out);
}

// Round 4
// 65.649 us; speedup vs baseline: 1.1707x; 1.0203x over previous
//
#include <hip/hip_runtime.h>

// DifferentiableHistogram: x (4,3,256,256) fp32, bin_centers (512,3) fp32
// (separable 8x8x8 grid), out (4,512) fp32.
//
// exp(-||p-c_ijk||^2 * 1250) = ex_i*ey_j*ez_k; denom = sx*sy*sz (separable).
// Known floor: harness poisons 256 MB d_ws -> ~40.4 us fillBuffer per timed
// call. Residual budget is ours.
//
// R4: per-wave sweep is an 8x64x64 GEMM -> mfma_f32_16x16x32_bf16.
//   A[m=lane&15][k=quad*8+j] = ex'[px][i]   (rows 8..15 zeroed in regs)
//   B[k=quad*8+j][n=lane&15] = ey[px][jn]*ez[px][kn],  n = nt*16+lane&15
//   C: col=lane&15, row=quad*4+reg  (quads 0..1 hold valid rows 0..7)
// Fused single reduce kernel (4 blocks x 1024) replaces reduce1+reduce2.

#define NPIX 65536
#define NB   4
#define BPB  256          // blocks per batch; 256 pixels per block
#define STR  260          // fp32 LDS row stride (1040 B, 16B-aligned rows)

typedef __attribute__((ext_vector_type(8))) short  short8;
typedef __attribute__((ext_vector_type(4))) float  floatx4;

__device__ __forceinline__ short bf16b(float f) {
    __bf16 h = (__bf16)f;
    return __builtin_bit_cast(short, h);
}

__global__ __launch_bounds__(256) void hist_accum(
    const float* __restrict__ x, const float* __restrict__ bc,
    float* __restrict__ ws)
{
    __shared__ __align__(16) float s_ex[8][STR];   // ex[i]*invS, col = pixel
    __shared__ __align__(16) float s_ey[8][STR];
    __shared__ __align__(16) float s_ez[8][STR];
    __shared__ float s_red[4][512];                // packed q=(j*8+k)*8+i

    const int tid   = threadIdx.x;
    const int b     = blockIdx.x >> 8;
    const int chunk = blockIdx.x & (BPB - 1);
    const int p     = chunk * 256 + tid;

    float cx[8], cy[8], cz[8];
#pragma unroll
    for (int i = 0; i < 8; ++i) {
        cx[i] = bc[i * 192 + 0];   // bin (i,j,k) at row i*64+j*8+k
        cy[i] = bc[i * 24 + 1];
        cz[i] = bc[i * 3 + 2];
    }

    // ---- stage: one pixel per thread ----
    const float* xb = x + (size_t)b * 3 * NPIX;
    const float r  = xb[p];
    const float g  = xb[NPIX + p];
    const float bl = xb[2 * NPIX + p];
    float exn[8], ey[8], ez[8];
    float sx = 0.f, sy = 0.f, sz = 0.f;
#pragma unroll
    for (int i = 0; i < 8; ++i) {
        float dx = r  - cx[i]; exn[i] = __expf(dx * dx * -1250.0f); sx += exn[i];
        float dy = g  - cy[i]; ey[i]  = __expf(dy * dy * -1250.0f); sy += ey[i];
        float dz = bl - cz[i]; ez[i]  = __expf(dz * dz * -1250.0f); sz += ez[i];
    }
    const float invS = 1.0f / (sx * sy * sz + 1e-8f);
#pragma unroll
    for (int i = 0; i < 8; ++i) {
        s_ex[i][tid] = exn[i] * invS;   // 2-way banked (free)
        s_ey[i][tid] = ey[i];
        s_ez[i][tid] = ez[i];
    }
    __syncthreads();

    // ---- MFMA sweep: wave w handles its own 64 pixels (K), M=i(8/16), N=jk(64)
    const int team = tid >> 6;
    const int lane = tid & 63;
    const int q0   = team * 64;
    const int m16  = lane & 15;
    const int quad = lane >> 4;
    const int kn   = lane & 7;          // ez row (n&7, same for all nt)
    const int jhi  = m16 >> 3;          // high bit of n within tile

    floatx4 cfr[4];
#pragma unroll
    for (int nt = 0; nt < 4; ++nt) cfr[nt] = (floatx4){0.f, 0.f, 0.f, 0.f};

#pragma unroll
    for (int ks = 0; ks < 2; ++ks) {
        const int px0 = q0 + ks * 32 + quad * 8;
        // A fragment: ex'[px0..px0+7][m16], rows >=8 are zero
        const float4 a0 = *(const float4*)&s_ex[m16 & 7][px0];
        const float4 a1 = *(const float4*)&s_ex[m16 & 7][px0 + 4];
        short8 af;
        af[0] = bf16b(a0.x); af[1] = bf16b(a0.y); af[2] = bf16b(a0.z); af[3] = bf16b(a0.w);
        af[4] = bf16b(a1.x); af[5] = bf16b(a1.y); af[6] = bf16b(a1.z); af[7] = bf16b(a1.w);
        if (m16 >= 8) {
#pragma unroll
            for (int e = 0; e < 8; ++e) af[e] = 0;
        }
        const float4 z0 = *(const float4*)&s_ez[kn][px0];
        const float4 z1 = *(const float4*)&s_ez[kn][px0 + 4];
#pragma unroll
        for (int nt = 0; nt < 4; ++nt) {
            const int jn = nt * 2 + jhi;      // ey row = n>>3
            const float4 y0 = *(const float4*)&s_ey[jn][px0];
            const float4 y1 = *(const float4*)&s_ey[jn][px0 + 4];
            short8 bfg;
            bfg[0] = bf16b(y0.x * z0.x); bfg[1] = bf16b(y0.y * z0.y);
            bfg[2] = bf16b(y0.z * z0.z); bfg[3] = bf16b(y0.w * z0.w);
            bfg[4] = bf16b(y1.x * z1.x); bfg[5] = bf16b(y1.y * z1.y);
            bfg[6] = bf16b(y1.z * z1.z); bfg[7] = bf16b(y1.w * z1.w);
            cfr[nt] = __builtin_amdgcn_mfma_f32_16x16x32_bf16(af, bfg, cfr[nt], 0, 0, 0);
        }
    }

    // ---- C extract: valid rows 0..7 live in quads 0..1 ----
    if (quad < 2) {
#pragma unroll
        for (int nt = 0; nt < 4; ++nt)
#pragma unroll
            for (int rr = 0; rr < 4; ++rr)
                s_red[team][(nt * 16 + m16) * 8 + quad * 4 + rr] = cfr[nt][rr];
    }
    __syncthreads();

    for (int q = tid; q < 512; q += 256) {
        const float v = s_red[0][q] + s_red[1][q] + s_red[2][q] + s_red[3][q];
        ws[(size_t)blockIdx.x * 512 + q] = v;
    }
}

// Fused reduce + L1 normalize: 4 blocks x 1024 threads, 512 KB reads/block.
__global__ __launch_bounds__(1024) void hist_reduce(
    const float* __restrict__ ws, float* __restrict__ out)
{
    __shared__ float s[8][512];
    __shared__ float s2[16];
    const int b = blockIdx.x;
    const int t = threadIdx.x;
    const int q4 = (t & 127) * 4;
    const int g  = t >> 7;                       // 0..7 chunk-groups
    const float* wb = ws + (size_t)b * BPB * 512;

    float4 v = make_float4(0.f, 0.f, 0.f, 0.f);
#pragma unroll 8
    for (int c = 0; c < 32; ++c) {
        const float4 u = *(const float4*)&wb[(size_t)(g * 32 + c) * 512 + q4];
        v.x += u.x; v.y += u.y; v.z += u.z; v.w += u.w;
    }
    *(float4*)&s[g][q4] = v;
    __syncthreads();

    float vq = 0.f;
    if (t < 512) {
#pragma unroll
        for (int g8 = 0; g8 < 8; ++g8) vq += s[g8][t];
    }
    float tot = vq;
#pragma unroll
    for (int off = 32; off > 0; off >>= 1) tot += __shfl_down(tot, off, 64);
    if ((t & 63) == 0) s2[t >> 6] = tot;
    __syncthreads();
    float S = 0.f;
#pragma unroll
    for (int i = 0; i < 8; ++i) S += s2[i];     // waves 8..15 contributed 0

    if (t < 512) {
        const int bin = ((t & 7) << 6) | (t >> 3);   // q=(j*8+k)*8+i -> i*64+j*8+k
        out[b * 512 + bin] = vq / (S + 1e-8f);
    }
}

extern "C" void kernel_launch(void* const* d_in, const int* in_sizes, int n_in,
                              void* d_out, int out_size, void* d_ws, size_t ws_size,
                              hipStream_t stream) {
    const float* x  = (const float*)d_in[0];
    const float* bc = (const float*)d_in[1];
    float* ws  = (float*)d_ws;                  // 1024*512 floats = 2 MB
    float* out = (float*)d_out;

    hist_accum<<<dim3(NB * BPB), dim3(256), 0, stream>>>(x, bc, ws);
    hist_reduce<<<dim3(NB), dim3(1024), 0, stream>>>(ws, out);
}